// Round 3
// baseline (328.897 us; speedup 1.0000x reference)
//
#include <hip/hip_runtime.h>
#include <hip/hip_bf16.h>
#include <cstdint>

#define N_NODES 10000
#define N_EDGES 160000
#define DIM 512
#define K1 1024
#define NEXP 4

typedef __bf16 bf16_t;
typedef bf16_t bf16x8 __attribute__((ext_vector_type(8)));
typedef float f32x4 __attribute__((ext_vector_type(4)));

#define AS1(p) ((__attribute__((address_space(1))) void*)(p))
#define AS3(p) ((__attribute__((address_space(3))) void*)(p))

// ---------------- zero counters ----------------
__global__ void zero_kernel(int* __restrict__ deg, int* __restrict__ ecnt) {
    int i = blockIdx.x * blockDim.x + threadIdx.x;
    if (i < N_NODES) deg[i] = 0;
    if (i < NEXP) ecnt[i] = 0;
}

// ---------------- gating + x->bf16 (no atomics) ----------------
__global__ void gate_kernel(const float* __restrict__ x,
                            const float* __restrict__ gw,
                            const float* __restrict__ gb,
                            int* __restrict__ top_idx,
                            float* __restrict__ top_val,
                            bf16_t* __restrict__ acat) {
    const int wave = threadIdx.x >> 6;
    const int lane = threadIdx.x & 63;
    const int node = blockIdx.x * 4 + wave;
    if (node >= N_NODES) return;
    const float4* x4 = (const float4*)(x + (size_t)node * DIM);
    const float4* gw4 = (const float4*)gw;
    float4 xa = x4[lane * 2];
    float4 xb = x4[lane * 2 + 1];
    float xv[8] = { xa.x, xa.y, xa.z, xa.w, xb.x, xb.y, xb.z, xb.w };
    float a0 = 0.f, a1 = 0.f, a2 = 0.f, a3 = 0.f;
    #pragma unroll
    for (int c = 0; c < 8; c++) {
        float4 g = gw4[lane * 8 + c];
        a0 += xv[c] * g.x; a1 += xv[c] * g.y; a2 += xv[c] * g.z; a3 += xv[c] * g.w;
    }
    bf16x8 o;
    #pragma unroll
    for (int c = 0; c < 8; c++) o[c] = (bf16_t)xv[c];
    *(bf16x8*)(acat + (size_t)node * K1 + DIM + lane * 8) = o;
    for (int off = 32; off > 0; off >>= 1) {
        a0 += __shfl_xor(a0, off);
        a1 += __shfl_xor(a1, off);
        a2 += __shfl_xor(a2, off);
        a3 += __shfl_xor(a3, off);
    }
    if (lane == 0) {
        float z[4] = { a0 + gb[0], a1 + gb[1], a2 + gb[2], a3 + gb[3] };
        int bi = 0; float bm = z[0];
        for (int e = 1; e < 4; e++) if (z[e] > bm) { bm = z[e]; bi = e; }
        float den = 0.f;
        for (int e = 0; e < 4; e++) den += expf(z[e] - bm);
        top_idx[node] = bi;
        top_val[node] = 1.0f / den;
    }
}

// ---------------- expert bucketing: LDS histogram ----------------
__global__ void bucket_kernel(const int* __restrict__ top_idx,
                              int* __restrict__ ecnt,
                              int* __restrict__ lists) {
    __shared__ int lcnt[NEXP];
    __shared__ int base[NEXP];
    const int tid = threadIdx.x;
    if (tid < NEXP) lcnt[tid] = 0;
    __syncthreads();
    const int node = blockIdx.x * 256 + tid;
    int e = 0, rank = 0;
    if (node < N_NODES) {
        e = top_idx[node];
        rank = atomicAdd(&lcnt[e], 1);
    }
    __syncthreads();
    if (tid < NEXP) base[tid] = atomicAdd(&ecnt[tid], lcnt[tid]);
    __syncthreads();
    if (node < N_NODES) lists[e * N_NODES + base[e] + rank] = node;
}

// ---------------- CSR build ----------------
__global__ void deg_kernel(const int* __restrict__ dst, int* __restrict__ deg) {
    int i = blockIdx.x * blockDim.x + threadIdx.x;
    if (i < N_EDGES) atomicAdd(&deg[dst[i]], 1);
}

__global__ void scan_kernel(const int* __restrict__ deg,
                            int* __restrict__ offs,
                            int* __restrict__ cursor) {
    __shared__ int wsum[16];
    __shared__ int carrysh;
    const int tid = threadIdx.x;
    const int lane = tid & 63;
    const int wv = tid >> 6;
    if (tid == 0) carrysh = 0;
    __syncthreads();
    for (int base = 0; base < N_NODES; base += 1024) {
        int i = base + tid;
        int v = (i < N_NODES) ? deg[i] : 0;
        int s = v;
        #pragma unroll
        for (int off = 1; off < 64; off <<= 1) {
            int t = __shfl_up(s, off);
            if (lane >= off) s += t;
        }
        if (lane == 63) wsum[wv] = s;
        int carry = carrysh;
        __syncthreads();
        if (wv == 0) {
            int w = (lane < 16) ? wsum[lane] : 0;
            #pragma unroll
            for (int off = 1; off < 16; off <<= 1) {
                int t = __shfl_up(w, off);
                if (lane >= off) w += t;
            }
            if (lane < 16) wsum[lane] = w;
        }
        __syncthreads();
        int wbase = (wv > 0) ? wsum[wv - 1] : 0;
        int excl = carry + wbase + s - v;
        if (i < N_NODES) { offs[i] = excl; cursor[i] = excl; }
        int total = wsum[15];
        __syncthreads();
        if (tid == 0) carrysh = carry + total;
        __syncthreads();
    }
    if (tid == 0) offs[N_NODES] = carrysh;
}

__global__ void fill_kernel(const int* __restrict__ src, const int* __restrict__ dst,
                            int* __restrict__ cursor, int* __restrict__ csr) {
    int i = blockIdx.x * blockDim.x + threadIdx.x;
    if (i < N_EDGES) {
        int d = dst[i];
        int p = atomicAdd(&cursor[d], 1);
        csr[p] = src[i];
    }
}

// ---------------- weight convert+transpose ----------------
__global__ void wtrans_kernel(const float* __restrict__ w_neigh,
                              const float* __restrict__ w_self,
                              bf16_t* __restrict__ Bt) {
    __shared__ float tile[32][33];
    const int m = blockIdx.z;
    const bool isSelf = m >= 8;
    const int el = m & 7;
    const float* W = (isSelf ? w_self : w_neigh) + (size_t)el * DIM * DIM;
    const int k0 = blockIdx.x * 32;
    const int n0 = blockIdx.y * 32;
    const int tx = threadIdx.x, ty = threadIdx.y;
    for (int r = ty; r < 32; r += 8)
        tile[r][tx] = W[(size_t)(k0 + r) * DIM + n0 + tx];
    __syncthreads();
    for (int r = ty; r < 32; r += 8) {
        int n = n0 + r;
        int k = k0 + tx;
        Bt[((size_t)el * DIM + n) * K1 + (isSelf ? DIM : 0) + k] = (bf16_t)tile[tx][r];
    }
}

// ---------------- agg1: mean of x rows into acat cols 0..511, unroll 4 ----------------
__global__ void agg1_kernel(const int* __restrict__ offs, const int* __restrict__ csr,
                            bf16_t* __restrict__ acat) {
    const int wave = threadIdx.x >> 6;
    const int lane = threadIdx.x & 63;
    const int node = blockIdx.x * 4 + wave;
    if (node >= N_NODES) return;
    const int c0 = lane * 8;
    float s[8] = {0,0,0,0,0,0,0,0};
    int beg = offs[node];
    int end = offs[node + 1];
    int d = end - beg;
    int p = beg;
    for (; p + 4 <= end; p += 4) {
        int i0 = csr[p], i1 = csr[p + 1], i2 = csr[p + 2], i3 = csr[p + 3];
        bf16x8 v0 = *(const bf16x8*)(acat + (size_t)i0 * K1 + DIM + c0);
        bf16x8 v1 = *(const bf16x8*)(acat + (size_t)i1 * K1 + DIM + c0);
        bf16x8 v2 = *(const bf16x8*)(acat + (size_t)i2 * K1 + DIM + c0);
        bf16x8 v3 = *(const bf16x8*)(acat + (size_t)i3 * K1 + DIM + c0);
        #pragma unroll
        for (int k = 0; k < 8; k++)
            s[k] += ((float)v0[k] + (float)v1[k]) + ((float)v2[k] + (float)v3[k]);
    }
    for (; p < end; p++) {
        int i0 = csr[p];
        bf16x8 v0 = *(const bf16x8*)(acat + (size_t)i0 * K1 + DIM + c0);
        #pragma unroll
        for (int k = 0; k < 8; k++) s[k] += (float)v0[k];
    }
    float w = d > 0 ? 1.0f / (float)d : 0.0f;
    bf16x8 o;
    #pragma unroll
    for (int k = 0; k < 8; k++) o[k] = (bf16_t)(s[k] * w);
    *(bf16x8*)(acat + (size_t)node * K1 + c0) = o;
}

// ---------------- agg2: selected-expert mean of h1 rows + self copy, unroll 4 ----------------
__global__ void agg2_kernel(const int* __restrict__ offs, const int* __restrict__ csr,
                            const int* __restrict__ top_idx,
                            const bf16_t* __restrict__ h1, bf16_t* __restrict__ acat) {
    const int wave = threadIdx.x >> 6;
    const int lane = threadIdx.x & 63;
    const int node = blockIdx.x * 4 + wave;
    if (node >= N_NODES) return;
    const int c0 = lane * 8;
    const bf16_t* hb = h1 + (size_t)top_idx[node] * N_NODES * DIM;
    float s[8] = {0,0,0,0,0,0,0,0};
    int beg = offs[node];
    int end = offs[node + 1];
    int d = end - beg;
    int p = beg;
    for (; p + 4 <= end; p += 4) {
        int i0 = csr[p], i1 = csr[p + 1], i2 = csr[p + 2], i3 = csr[p + 3];
        bf16x8 v0 = *(const bf16x8*)(hb + (size_t)i0 * DIM + c0);
        bf16x8 v1 = *(const bf16x8*)(hb + (size_t)i1 * DIM + c0);
        bf16x8 v2 = *(const bf16x8*)(hb + (size_t)i2 * DIM + c0);
        bf16x8 v3 = *(const bf16x8*)(hb + (size_t)i3 * DIM + c0);
        #pragma unroll
        for (int k = 0; k < 8; k++)
            s[k] += ((float)v0[k] + (float)v1[k]) + ((float)v2[k] + (float)v3[k]);
    }
    for (; p < end; p++) {
        int i0 = csr[p];
        bf16x8 v0 = *(const bf16x8*)(hb + (size_t)i0 * DIM + c0);
        #pragma unroll
        for (int k = 0; k < 8; k++) s[k] += (float)v0[k];
    }
    float w = d > 0 ? 1.0f / (float)d : 0.0f;
    bf16x8 o;
    #pragma unroll
    for (int k = 0; k < 8; k++) o[k] = (bf16_t)(s[k] * w);
    *(bf16x8*)(acat + (size_t)node * K1 + c0) = o;
    *(bf16x8*)(acat + (size_t)node * K1 + DIM + c0) = *(const bf16x8*)(hb + (size_t)node * DIM + c0);
}

// ---------------- GEMM: C = A[M,1024] @ Bt[n][k]^T, 128x128 tile, BK=64 ----------------
// LDS layout: 16 panels per operand; panel p = 2*rblk + h (rblk=row/16, h=k-half)
// within panel: chunk-major — addr = p*512 + chunk*128 + row*8 (elements)
// => fragment ds_read_b128 is 1KB contiguous per wave: conflict-free.
template <int MODE>
__global__ __launch_bounds__(256)
void gemm_kernel(const bf16_t* __restrict__ A,
                 const bf16_t* __restrict__ Bt,
                 const int layer,
                 const float* __restrict__ bias_all,
                 bf16_t* __restrict__ h1,
                 float* __restrict__ out,
                 const int* __restrict__ lists,
                 const int* __restrict__ ecnt,
                 const float* __restrict__ top_val) {
    const int e = blockIdx.z;
    int cnt = N_NODES;
    if (MODE == 1) {
        cnt = ecnt[e];
        if ((int)(blockIdx.y * 128) >= cnt) return;
    }
    __shared__ __align__(16) bf16_t As[128 * 64];
    __shared__ __align__(16) bf16_t Bs[128 * 64];

    const int t = threadIdx.x;
    const int lane = t & 63;
    const int wave = t >> 6;
    const int wm = wave >> 1;
    const int wn = wave & 1;
    const int wa = wave >> 1;   // staging rblk offset
    const int wh = wave & 1;    // staging k-half
    const int lr = t & 15;      // row within panel
    const int lc = (t >> 4) & 3;// chunk within panel

    const bf16_t* Bte = Bt + (size_t)(e * 2 + layer) * DIM * K1;
    const bf16_t* aptr[4];
    const bf16_t* bptr[4];
    #pragma unroll
    for (int j = 0; j < 4; j++) {
        int rb = 2 * j + wa;                     // rblk 0..7
        int i0 = blockIdx.y * 128 + rb * 16 + lr;
        int arow;
        if (MODE == 0) arow = min(i0, N_NODES - 1);
        else           arow = lists[e * N_NODES + min(i0, cnt - 1)];
        aptr[j] = A + (size_t)arow * K1 + wh * 32 + lc * 8;
        int brow = blockIdx.x * 128 + rb * 16 + lr;
        bptr[j] = Bte + (size_t)brow * K1 + wh * 32 + lc * 8;
    }

    f32x4 acc[4][4] = {};
    char* asb = (char*)&As[0];
    char* bsb = (char*)&Bs[0];

    for (int k0 = 0; k0 < K1; k0 += 64) {
        __syncthreads();
        #pragma unroll
        for (int j = 0; j < 4; j++)
            __builtin_amdgcn_global_load_lds(AS1(aptr[j]), AS3(asb + (4 * j + wave) * 1024), 16, 0, 0);
        #pragma unroll
        for (int j = 0; j < 4; j++)
            __builtin_amdgcn_global_load_lds(AS1(bptr[j]), AS3(bsb + (4 * j + wave) * 1024), 16, 0, 0);
        __syncthreads();
        #pragma unroll
        for (int h = 0; h < 2; h++) {
            bf16x8 af[4], bfr[4];
            #pragma unroll
            for (int i = 0; i < 4; i++)
                af[i] = *(const bf16x8*)(As + (8 * wm + 2 * i + h) * 512 + (lane >> 4) * 128 + (lane & 15) * 8);
            #pragma unroll
            for (int j = 0; j < 4; j++)
                bfr[j] = *(const bf16x8*)(Bs + (8 * wn + 2 * j + h) * 512 + (lane >> 4) * 128 + (lane & 15) * 8);
            #pragma unroll
            for (int i = 0; i < 4; i++)
                #pragma unroll
                for (int j = 0; j < 4; j++)
                    acc[i][j] = __builtin_amdgcn_mfma_f32_16x16x32_bf16(af[i], bfr[j], acc[i][j], 0, 0, 0);
        }
        #pragma unroll
        for (int j = 0; j < 4; j++) { aptr[j] += 64; bptr[j] += 64; }
    }

    // epilogue; C/D layout: col=lane&15, row=(lane>>4)*4+r
    const float* bias = bias_all + e * 1024 + layer * DIM;
    const int cbase = blockIdx.x * 128 + wn * 64 + (lane & 15);
    float bv[4];
    #pragma unroll
    for (int j = 0; j < 4; j++) bv[j] = bias[cbase + j * 16];
    #pragma unroll
    for (int i = 0; i < 4; i++) {
        #pragma unroll
        for (int r = 0; r < 4; r++) {
            int row = blockIdx.y * 128 + wm * 64 + i * 16 + (lane >> 4) * 4 + r;
            if (MODE == 0) {
                if (row < N_NODES) {
                    bf16_t* cp = h1 + ((size_t)e * N_NODES + row) * DIM + cbase;
                    #pragma unroll
                    for (int j = 0; j < 4; j++) {
                        float v = fmaxf(acc[i][j][r] + bv[j], 0.f);
                        cp[j * 16] = (bf16_t)v;
                    }
                }
            } else {
                if (row < cnt) {
                    int node = lists[e * N_NODES + row];
                    float tv = top_val[node];
                    float* cp = out + (size_t)node * DIM + cbase;
                    #pragma unroll
                    for (int j = 0; j < 4; j++) {
                        float v = fmaxf(acc[i][j][r] + bv[j], 0.f);
                        cp[j * 16] = v * tv;
                    }
                }
            }
        }
    }
}

extern "C" void kernel_launch(void* const* d_in, const int* in_sizes, int n_in,
                              void* d_out, int out_size, void* d_ws, size_t ws_size,
                              hipStream_t stream) {
    const float* x       = (const float*)d_in[0];
    const int*   edge    = (const int*)d_in[1];
    const float* gw      = (const float*)d_in[2];
    const float* gb      = (const float*)d_in[3];
    const float* w_self  = (const float*)d_in[4];
    const float* w_neigh = (const float*)d_in[5];
    const float* b_exp   = (const float*)d_in[6];
    float* out = (float*)d_out;

    char* p = (char*)d_ws;
    auto alloc = [&](size_t bytes) {
        char* r = p;
        p += (bytes + 255) & ~(size_t)255;
        return r;
    };
    bf16_t* Bt      = (bf16_t*)alloc((size_t)8 * DIM * K1 * 2);
    bf16_t* acat    = (bf16_t*)alloc((size_t)N_NODES * K1 * 2);
    bf16_t* h1      = (bf16_t*)alloc((size_t)NEXP * N_NODES * DIM * 2);
    int*    deg     = (int*)alloc((size_t)N_NODES * 4);
    int*    offs    = (int*)alloc((size_t)(N_NODES + 1) * 4);
    int*    cursor  = (int*)alloc((size_t)N_NODES * 4);
    int*    csr     = (int*)alloc((size_t)N_EDGES * 4);
    int*    top_idx = (int*)alloc((size_t)N_NODES * 4);
    float*  top_val = (float*)alloc((size_t)N_NODES * 4);
    int*    ecnt    = (int*)alloc(256);
    int*    lists   = (int*)alloc((size_t)NEXP * N_NODES * 4);

    const int* srcE = edge;
    const int* dstE = edge + N_EDGES;

    zero_kernel<<<40, 256, 0, stream>>>(deg, ecnt);
    gate_kernel<<<N_NODES / 4, 256, 0, stream>>>(x, gw, gb, top_idx, top_val, acat);
    bucket_kernel<<<40, 256, 0, stream>>>(top_idx, ecnt, lists);
    deg_kernel<<<N_EDGES / 256, 256, 0, stream>>>(dstE, deg);
    scan_kernel<<<1, 1024, 0, stream>>>(deg, offs, cursor);
    fill_kernel<<<N_EDGES / 256, 256, 0, stream>>>(srcE, dstE, cursor, csr);
    wtrans_kernel<<<dim3(16, 16, 16), dim3(32, 8), 0, stream>>>(w_neigh, w_self, Bt);
    agg1_kernel<<<N_NODES / 4, 256, 0, stream>>>(offs, csr, acat);
    gemm_kernel<0><<<dim3(4, 79, 4), 256, 0, stream>>>(acat, Bt, 0, b_exp, h1, nullptr, nullptr, nullptr, nullptr);
    agg2_kernel<<<N_NODES / 4, 256, 0, stream>>>(offs, csr, top_idx, h1, acat);
    gemm_kernel<1><<<dim3(4, 79, 4), 256, 0, stream>>>(acat, Bt, 1, b_exp, nullptr, out, lists, ecnt, top_val);
}

// Round 6
// 325.903 us; speedup vs baseline: 1.0092x; 1.0092x over previous
//
#include <hip/hip_runtime.h>
#include <hip/hip_bf16.h>
#include <cstdint>

#define N_NODES 10000
#define N_EDGES 160000
#define DIM 512
#define K1 1024
#define NEXP 4

typedef __bf16 bf16_t;
typedef bf16_t bf16x8 __attribute__((ext_vector_type(8)));
typedef float f32x4 __attribute__((ext_vector_type(4)));

#define AS1(p) ((__attribute__((address_space(1))) void*)(p))
#define AS3(p) ((__attribute__((address_space(3))) void*)(p))

// ---------------- zero counters ----------------
__global__ void zero_kernel(int* __restrict__ deg, int* __restrict__ ecnt) {
    int i = blockIdx.x * blockDim.x + threadIdx.x;
    if (i < N_NODES) deg[i] = 0;
    if (i < NEXP) ecnt[i] = 0;
}

// ---------------- gating + x->bf16 (no atomics) ----------------
__global__ void gate_kernel(const float* __restrict__ x,
                            const float* __restrict__ gw,
                            const float* __restrict__ gb,
                            int* __restrict__ top_idx,
                            float* __restrict__ top_val,
                            bf16_t* __restrict__ acat) {
    const int wave = threadIdx.x >> 6;
    const int lane = threadIdx.x & 63;
    const int node = blockIdx.x * 4 + wave;
    if (node >= N_NODES) return;
    const float4* x4 = (const float4*)(x + (size_t)node * DIM);
    const float4* gw4 = (const float4*)gw;
    float4 xa = x4[lane * 2];
    float4 xb = x4[lane * 2 + 1];
    float xv[8] = { xa.x, xa.y, xa.z, xa.w, xb.x, xb.y, xb.z, xb.w };
    float a0 = 0.f, a1 = 0.f, a2 = 0.f, a3 = 0.f;
    #pragma unroll
    for (int c = 0; c < 8; c++) {
        float4 g = gw4[lane * 8 + c];
        a0 += xv[c] * g.x; a1 += xv[c] * g.y; a2 += xv[c] * g.z; a3 += xv[c] * g.w;
    }
    bf16x8 o;
    #pragma unroll
    for (int c = 0; c < 8; c++) o[c] = (bf16_t)xv[c];
    *(bf16x8*)(acat + (size_t)node * K1 + DIM + lane * 8) = o;
    for (int off = 32; off > 0; off >>= 1) {
        a0 += __shfl_xor(a0, off);
        a1 += __shfl_xor(a1, off);
        a2 += __shfl_xor(a2, off);
        a3 += __shfl_xor(a3, off);
    }
    if (lane == 0) {
        float z[4] = { a0 + gb[0], a1 + gb[1], a2 + gb[2], a3 + gb[3] };
        int bi = 0; float bm = z[0];
        for (int e = 1; e < 4; e++) if (z[e] > bm) { bm = z[e]; bi = e; }
        float den = 0.f;
        for (int e = 0; e < 4; e++) den += expf(z[e] - bm);
        top_idx[node] = bi;
        top_val[node] = 1.0f / den;
    }
}

// ---------------- expert bucketing ----------------
__global__ void bucket_kernel(const int* __restrict__ top_idx,
                              int* __restrict__ ecnt,
                              int* __restrict__ lists) {
    __shared__ int lcnt[NEXP];
    __shared__ int base[NEXP];
    const int tid = threadIdx.x;
    if (tid < NEXP) lcnt[tid] = 0;
    __syncthreads();
    const int node = blockIdx.x * 256 + tid;
    int e = 0, rank = 0;
    if (node < N_NODES) {
        e = top_idx[node];
        rank = atomicAdd(&lcnt[e], 1);
    }
    __syncthreads();
    if (tid < NEXP) base[tid] = atomicAdd(&ecnt[tid], lcnt[tid]);
    __syncthreads();
    if (node < N_NODES) lists[e * N_NODES + base[e] + rank] = node;
}

// ---------------- CSR build ----------------
__global__ void deg_kernel(const int* __restrict__ dst, int* __restrict__ deg) {
    int i = blockIdx.x * blockDim.x + threadIdx.x;
    if (i < N_EDGES) atomicAdd(&deg[dst[i]], 1);
}

__global__ void scan_kernel(const int* __restrict__ deg,
                            int* __restrict__ offs,
                            int* __restrict__ cursor) {
    __shared__ int wsum[16];
    __shared__ int carrysh;
    const int tid = threadIdx.x;
    const int lane = tid & 63;
    const int wv = tid >> 6;
    if (tid == 0) carrysh = 0;
    __syncthreads();
    for (int base = 0; base < N_NODES; base += 1024) {
        int i = base + tid;
        int v = (i < N_NODES) ? deg[i] : 0;
        int s = v;
        #pragma unroll
        for (int off = 1; off < 64; off <<= 1) {
            int t = __shfl_up(s, off);
            if (lane >= off) s += t;
        }
        if (lane == 63) wsum[wv] = s;
        int carry = carrysh;
        __syncthreads();
        if (wv == 0) {
            int w = (lane < 16) ? wsum[lane] : 0;
            #pragma unroll
            for (int off = 1; off < 16; off <<= 1) {
                int t = __shfl_up(w, off);
                if (lane >= off) w += t;
            }
            if (lane < 16) wsum[lane] = w;
        }
        __syncthreads();
        int wbase = (wv > 0) ? wsum[wv - 1] : 0;
        int excl = carry + wbase + s - v;
        if (i < N_NODES) { offs[i] = excl; cursor[i] = excl; }
        int total = wsum[15];
        __syncthreads();
        if (tid == 0) carrysh = carry + total;
        __syncthreads();
    }
    if (tid == 0) offs[N_NODES] = carrysh;
}

__global__ void fill_kernel(const int* __restrict__ src, const int* __restrict__ dst,
                            int* __restrict__ cursor, int* __restrict__ csr) {
    int i = blockIdx.x * blockDim.x + threadIdx.x;
    if (i < N_EDGES) {
        int d = dst[i];
        int p = atomicAdd(&cursor[d], 1);
        csr[p] = src[i];
    }
}

// ---------------- weight convert+transpose ----------------
__global__ void wtrans_kernel(const float* __restrict__ w_neigh,
                              const float* __restrict__ w_self,
                              bf16_t* __restrict__ Bt) {
    __shared__ float tile[32][33];
    const int m = blockIdx.z;
    const bool isSelf = m >= 8;
    const int el = m & 7;
    const float* W = (isSelf ? w_self : w_neigh) + (size_t)el * DIM * DIM;
    const int k0 = blockIdx.x * 32;
    const int n0 = blockIdx.y * 32;
    const int tx = threadIdx.x, ty = threadIdx.y;
    for (int r = ty; r < 32; r += 8)
        tile[r][tx] = W[(size_t)(k0 + r) * DIM + n0 + tx];
    __syncthreads();
    for (int r = ty; r < 32; r += 8) {
        int n = n0 + r;
        int k = k0 + tx;
        Bt[((size_t)el * DIM + n) * K1 + (isSelf ? DIM : 0) + k] = (bf16_t)tile[tx][r];
    }
}

// ---------------- agg1: mean of x rows into acat cols 0..511, unroll 8 ----------------
__global__ void agg1_kernel(const int* __restrict__ offs, const int* __restrict__ csr,
                            bf16_t* __restrict__ acat) {
    const int wave = threadIdx.x >> 6;
    const int lane = threadIdx.x & 63;
    const int node = blockIdx.x * 4 + wave;
    if (node >= N_NODES) return;
    const int c0 = lane * 8;
    float s[8] = {0,0,0,0,0,0,0,0};
    int beg = offs[node];
    int end = offs[node + 1];
    int d = end - beg;
    int p = beg;
    for (; p + 8 <= end; p += 8) {
        bf16x8 v[8];
        #pragma unroll
        for (int q = 0; q < 8; q++) {
            int idx = csr[p + q];
            v[q] = *(const bf16x8*)(acat + (size_t)idx * K1 + DIM + c0);
        }
        #pragma unroll
        for (int q = 0; q < 8; q++)
            #pragma unroll
            for (int k = 0; k < 8; k++) s[k] += (float)v[q][k];
    }
    for (; p + 4 <= end; p += 4) {
        bf16x8 v[4];
        #pragma unroll
        for (int q = 0; q < 4; q++) {
            int idx = csr[p + q];
            v[q] = *(const bf16x8*)(acat + (size_t)idx * K1 + DIM + c0);
        }
        #pragma unroll
        for (int q = 0; q < 4; q++)
            #pragma unroll
            for (int k = 0; k < 8; k++) s[k] += (float)v[q][k];
    }
    for (; p < end; p++) {
        int idx = csr[p];
        bf16x8 v0 = *(const bf16x8*)(acat + (size_t)idx * K1 + DIM + c0);
        #pragma unroll
        for (int k = 0; k < 8; k++) s[k] += (float)v0[k];
    }
    float w = d > 0 ? 1.0f / (float)d : 0.0f;
    bf16x8 o;
    #pragma unroll
    for (int k = 0; k < 8; k++) o[k] = (bf16_t)(s[k] * w);
    *(bf16x8*)(acat + (size_t)node * K1 + c0) = o;
}

// ---------------- agg2: selected-expert mean of h1 rows + self copy, unroll 8 ----------------
__global__ void agg2_kernel(const int* __restrict__ offs, const int* __restrict__ csr,
                            const int* __restrict__ top_idx,
                            const bf16_t* __restrict__ h1, bf16_t* __restrict__ acat) {
    const int wave = threadIdx.x >> 6;
    const int lane = threadIdx.x & 63;
    const int node = blockIdx.x * 4 + wave;
    if (node >= N_NODES) return;
    const int c0 = lane * 8;
    const bf16_t* hb = h1 + (size_t)top_idx[node] * N_NODES * DIM;
    float s[8] = {0,0,0,0,0,0,0,0};
    int beg = offs[node];
    int end = offs[node + 1];
    int d = end - beg;
    int p = beg;
    for (; p + 8 <= end; p += 8) {
        bf16x8 v[8];
        #pragma unroll
        for (int q = 0; q < 8; q++) {
            int idx = csr[p + q];
            v[q] = *(const bf16x8*)(hb + (size_t)idx * DIM + c0);
        }
        #pragma unroll
        for (int q = 0; q < 8; q++)
            #pragma unroll
            for (int k = 0; k < 8; k++) s[k] += (float)v[q][k];
    }
    for (; p + 4 <= end; p += 4) {
        bf16x8 v[4];
        #pragma unroll
        for (int q = 0; q < 4; q++) {
            int idx = csr[p + q];
            v[q] = *(const bf16x8*)(hb + (size_t)idx * DIM + c0);
        }
        #pragma unroll
        for (int q = 0; q < 4; q++)
            #pragma unroll
            for (int k = 0; k < 8; k++) s[k] += (float)v[q][k];
    }
    for (; p < end; p++) {
        int idx = csr[p];
        bf16x8 v0 = *(const bf16x8*)(hb + (size_t)idx * DIM + c0);
        #pragma unroll
        for (int k = 0; k < 8; k++) s[k] += (float)v0[k];
    }
    float w = d > 0 ? 1.0f / (float)d : 0.0f;
    bf16x8 o;
    #pragma unroll
    for (int k = 0; k < 8; k++) o[k] = (bf16_t)(s[k] * w);
    *(bf16x8*)(acat + (size_t)node * K1 + c0) = o;
    *(bf16x8*)(acat + (size_t)node * K1 + DIM + c0) = *(const bf16x8*)(hb + (size_t)node * DIM + c0);
}

// ---------------- GEMM: 128x128 tile, BK=32, conflict-free chunk-major LDS ----------------
// LDS: 8 panels/operand; panel p = rows [p*16, p*16+16), stored [chunk(4)][row(16)][8elem]
// staging: wave w loads panels {w, w+4}; lane l -> row l&15, chunk l>>4; dest = p*1024 + l*16 bytes
// fragment: af[i] = panel wm*4+i, addr = p*512 + (lane>>4)*128 + (lane&15)*8 elems — 1KB contiguous/wave
// MODE 0: 1D grid 1280 blocks, XCD-clustered decode (xcd = b&7 -> y-quarter, expert-pair)
// MODE 1: grid (4, ceil(cnt/128), 4), row gather via lists
template <int MODE>
__global__ __launch_bounds__(256)
void gemm_kernel(const bf16_t* __restrict__ A,
                 const bf16_t* __restrict__ Bt,
                 const int layer,
                 const float* __restrict__ bias_all,
                 bf16_t* __restrict__ h1,
                 float* __restrict__ out,
                 const int* __restrict__ lists,
                 const int* __restrict__ ecnt,
                 const float* __restrict__ top_val) {
    int bx, by, e;
    if (MODE == 0) {
        // XCD-clustered: xcd owns a y-quarter x expert-pair; A slice streams once per pair
        const int b = blockIdx.x;
        const int kq = b & 7;          // XCD id under round-robin dispatch (perf heuristic only)
        const int ke = kq >> 2;        // expert pair 0..1
        const int ky = kq & 3;         // y quarter 0..3
        const int r = b >> 3;          // 0..159
        const int yloc = r >> 3;       // 0..19
        const int xz = r & 7;
        bx = xz & 3;
        e = ke * 2 + (xz >> 2);
        by = ky * 20 + yloc;
        if (by >= 79) return;
    } else {
        bx = blockIdx.x; by = blockIdx.y; e = blockIdx.z;
    }
    int cnt = N_NODES;
    if (MODE == 1) {
        cnt = ecnt[e];
        if (by * 128 >= cnt) return;
    }
    __shared__ __align__(16) bf16_t As[128 * 32];
    __shared__ __align__(16) bf16_t Bs[128 * 32];

    const int t = threadIdx.x;
    const int lane = t & 63;
    const int wave = t >> 6;
    const int wm = wave >> 1;
    const int wn = wave & 1;
    const int lr = lane & 15;      // row within panel
    const int lc = lane >> 4;      // chunk within panel

    const int pa0 = wave, pa1 = wave + 4;
    int i0 = by * 128 + pa0 * 16 + lr;
    int i1 = by * 128 + pa1 * 16 + lr;
    int arow0, arow1;
    if (MODE == 0) {
        arow0 = min(i0, N_NODES - 1);
        arow1 = min(i1, N_NODES - 1);
    } else {
        arow0 = lists[e * N_NODES + min(i0, cnt - 1)];
        arow1 = lists[e * N_NODES + min(i1, cnt - 1)];
    }
    const bf16_t* Bte = Bt + (size_t)(e * 2 + layer) * DIM * K1;
    const bf16_t* aptr0 = A + (size_t)arow0 * K1 + lc * 8;
    const bf16_t* aptr1 = A + (size_t)arow1 * K1 + lc * 8;
    const bf16_t* bptr0 = Bte + (size_t)(bx * 128 + pa0 * 16 + lr) * K1 + lc * 8;
    const bf16_t* bptr1 = Bte + (size_t)(bx * 128 + pa1 * 16 + lr) * K1 + lc * 8;

    f32x4 acc[4][4] = {};
    char* asb = (char*)&As[0];
    char* bsb = (char*)&Bs[0];

    for (int k0 = 0; k0 < K1; k0 += 32) {
        __syncthreads();
        __builtin_amdgcn_global_load_lds(AS1(aptr0), AS3(asb + pa0 * 1024), 16, 0, 0);
        __builtin_amdgcn_global_load_lds(AS1(aptr1), AS3(asb + pa1 * 1024), 16, 0, 0);
        __builtin_amdgcn_global_load_lds(AS1(bptr0), AS3(bsb + pa0 * 1024), 16, 0, 0);
        __builtin_amdgcn_global_load_lds(AS1(bptr1), AS3(bsb + pa1 * 1024), 16, 0, 0);
        __syncthreads();
        bf16x8 af[4], bfr[4];
        #pragma unroll
        for (int i = 0; i < 4; i++)
            af[i] = *(const bf16x8*)(As + (wm * 4 + i) * 512 + (lane >> 4) * 128 + (lane & 15) * 8);
        #pragma unroll
        for (int j = 0; j < 4; j++)
            bfr[j] = *(const bf16x8*)(Bs + (wn * 4 + j) * 512 + (lane >> 4) * 128 + (lane & 15) * 8);
        #pragma unroll
        for (int i = 0; i < 4; i++)
            #pragma unroll
            for (int j = 0; j < 4; j++)
                acc[i][j] = __builtin_amdgcn_mfma_f32_16x16x32_bf16(af[i], bfr[j], acc[i][j], 0, 0, 0);
        aptr0 += 32; aptr1 += 32; bptr0 += 32; bptr1 += 32;
    }

    // epilogue; C/D layout: col=lane&15, row=(lane>>4)*4+r
    const float* bias = bias_all + e * 1024 + layer * DIM;
    const int cbase = bx * 128 + wn * 64 + (lane & 15);
    float bv[4];
    #pragma unroll
    for (int j = 0; j < 4; j++) bv[j] = bias[cbase + j * 16];
    #pragma unroll
    for (int i = 0; i < 4; i++) {
        #pragma unroll
        for (int r = 0; r < 4; r++) {
            int row = by * 128 + wm * 64 + i * 16 + (lane >> 4) * 4 + r;
            if (MODE == 0) {
                if (row < N_NODES) {
                    bf16_t* cp = h1 + ((size_t)e * N_NODES + row) * DIM + cbase;
                    #pragma unroll
                    for (int j = 0; j < 4; j++) {
                        float v = fmaxf(acc[i][j][r] + bv[j], 0.f);
                        cp[j * 16] = (bf16_t)v;
                    }
                }
            } else {
                if (row < cnt) {
                    int node = lists[e * N_NODES + row];
                    float tv = top_val[node];
                    float* cp = out + (size_t)node * DIM + cbase;
                    #pragma unroll
                    for (int j = 0; j < 4; j++) {
                        float v = fmaxf(acc[i][j][r] + bv[j], 0.f);
                        cp[j * 16] = v * tv;
                    }
                }
            }
        }
    }
}

extern "C" void kernel_launch(void* const* d_in, const int* in_sizes, int n_in,
                              void* d_out, int out_size, void* d_ws, size_t ws_size,
                              hipStream_t stream) {
    const float* x       = (const float*)d_in[0];
    const int*   edge    = (const int*)d_in[1];
    const float* gw      = (const float*)d_in[2];
    const float* gb      = (const float*)d_in[3];
    const float* w_self  = (const float*)d_in[4];
    const float* w_neigh = (const float*)d_in[5];
    const float* b_exp   = (const float*)d_in[6];
    float* out = (float*)d_out;

    char* p = (char*)d_ws;
    auto alloc = [&](size_t bytes) {
        char* r = p;
        p += (bytes + 255) & ~(size_t)255;
        return r;
    };
    bf16_t* Bt      = (bf16_t*)alloc((size_t)8 * DIM * K1 * 2);
    bf16_t* acat    = (bf16_t*)alloc((size_t)N_NODES * K1 * 2);
    bf16_t* h1      = (bf16_t*)alloc((size_t)NEXP * N_NODES * DIM * 2);
    int*    deg     = (int*)alloc((size_t)N_NODES * 4);
    int*    offs    = (int*)alloc((size_t)(N_NODES + 1) * 4);
    int*    cursor  = (int*)alloc((size_t)N_NODES * 4);
    int*    csr     = (int*)alloc((size_t)N_EDGES * 4);
    int*    top_idx = (int*)alloc((size_t)N_NODES * 4);
    float*  top_val = (float*)alloc((size_t)N_NODES * 4);
    int*    ecnt    = (int*)alloc(256);
    int*    lists   = (int*)alloc((size_t)NEXP * N_NODES * 4);

    const int* srcE = edge;
    const int* dstE = edge + N_EDGES;

    zero_kernel<<<40, 256, 0, stream>>>(deg, ecnt);
    gate_kernel<<<N_NODES / 4, 256, 0, stream>>>(x, gw, gb, top_idx, top_val, acat);
    bucket_kernel<<<40, 256, 0, stream>>>(top_idx, ecnt, lists);
    deg_kernel<<<N_EDGES / 256, 256, 0, stream>>>(dstE, deg);
    scan_kernel<<<1, 1024, 0, stream>>>(deg, offs, cursor);
    fill_kernel<<<N_EDGES / 256, 256, 0, stream>>>(srcE, dstE, cursor, csr);
    wtrans_kernel<<<dim3(16, 16, 16), dim3(32, 8), 0, stream>>>(w_neigh, w_self, Bt);
    agg1_kernel<<<N_NODES / 4, 256, 0, stream>>>(offs, csr, acat);
    gemm_kernel<0><<<1280, 256, 0, stream>>>(acat, Bt, 0, b_exp, h1, nullptr, nullptr, nullptr, nullptr);
    agg2_kernel<<<N_NODES / 4, 256, 0, stream>>>(offs, csr, top_idx, h1, acat);
    gemm_kernel<1><<<dim3(4, 79, 4), 256, 0, stream>>>(acat, Bt, 1, b_exp, nullptr, out, lists, ecnt, top_val);
}

// Round 7
// 276.534 us; speedup vs baseline: 1.1894x; 1.1785x over previous
//
#include <hip/hip_runtime.h>
#include <hip/hip_bf16.h>
#include <cstdint>

#define N_NODES 10000
#define N_EDGES 160000
#define DIM 512
#define K1 1024
#define NEXP 4

typedef __bf16 bf16_t;
typedef bf16_t bf16x8 __attribute__((ext_vector_type(8)));
typedef float f32x4 __attribute__((ext_vector_type(4)));

#define AS1(p) ((__attribute__((address_space(1))) void*)(p))
#define AS3(p) ((__attribute__((address_space(3))) void*)(p))

// ---------------- zero counters ----------------
__global__ void zero_kernel(int* __restrict__ deg, int* __restrict__ ecnt) {
    int i = blockIdx.x * blockDim.x + threadIdx.x;
    if (i < N_NODES) deg[i] = 0;
    if (i < NEXP) ecnt[i] = 0;
}

// ---------------- gating + x->bf16 (no atomics) ----------------
__global__ void gate_kernel(const float* __restrict__ x,
                            const float* __restrict__ gw,
                            const float* __restrict__ gb,
                            int* __restrict__ top_idx,
                            float* __restrict__ top_val,
                            bf16_t* __restrict__ acat) {
    const int wave = threadIdx.x >> 6;
    const int lane = threadIdx.x & 63;
    const int node = blockIdx.x * 4 + wave;
    if (node >= N_NODES) return;
    const float4* x4 = (const float4*)(x + (size_t)node * DIM);
    const float4* gw4 = (const float4*)gw;
    float4 xa = x4[lane * 2];
    float4 xb = x4[lane * 2 + 1];
    float xv[8] = { xa.x, xa.y, xa.z, xa.w, xb.x, xb.y, xb.z, xb.w };
    float a0 = 0.f, a1 = 0.f, a2 = 0.f, a3 = 0.f;
    #pragma unroll
    for (int c = 0; c < 8; c++) {
        float4 g = gw4[lane * 8 + c];
        a0 += xv[c] * g.x; a1 += xv[c] * g.y; a2 += xv[c] * g.z; a3 += xv[c] * g.w;
    }
    bf16x8 o;
    #pragma unroll
    for (int c = 0; c < 8; c++) o[c] = (bf16_t)xv[c];
    *(bf16x8*)(acat + (size_t)node * K1 + DIM + lane * 8) = o;
    for (int off = 32; off > 0; off >>= 1) {
        a0 += __shfl_xor(a0, off);
        a1 += __shfl_xor(a1, off);
        a2 += __shfl_xor(a2, off);
        a3 += __shfl_xor(a3, off);
    }
    if (lane == 0) {
        float z[4] = { a0 + gb[0], a1 + gb[1], a2 + gb[2], a3 + gb[3] };
        int bi = 0; float bm = z[0];
        for (int e = 1; e < 4; e++) if (z[e] > bm) { bm = z[e]; bi = e; }
        float den = 0.f;
        for (int e = 0; e < 4; e++) den += expf(z[e] - bm);
        top_idx[node] = bi;
        top_val[node] = 1.0f / den;
    }
}

// ---------------- expert bucketing ----------------
__global__ void bucket_kernel(const int* __restrict__ top_idx,
                              int* __restrict__ ecnt,
                              int* __restrict__ lists) {
    __shared__ int lcnt[NEXP];
    __shared__ int base[NEXP];
    const int tid = threadIdx.x;
    if (tid < NEXP) lcnt[tid] = 0;
    __syncthreads();
    const int node = blockIdx.x * 256 + tid;
    int e = 0, rank = 0;
    if (node < N_NODES) {
        e = top_idx[node];
        rank = atomicAdd(&lcnt[e], 1);
    }
    __syncthreads();
    if (tid < NEXP) base[tid] = atomicAdd(&ecnt[tid], lcnt[tid]);
    __syncthreads();
    if (node < N_NODES) lists[e * N_NODES + base[e] + rank] = node;
}

// ---------------- CSR build ----------------
__global__ void deg_kernel(const int* __restrict__ dst, int* __restrict__ deg) {
    int i = blockIdx.x * blockDim.x + threadIdx.x;
    if (i < N_EDGES) atomicAdd(&deg[dst[i]], 1);
}

__global__ void scan_kernel(const int* __restrict__ deg,
                            int* __restrict__ offs,
                            int* __restrict__ cursor) {
    __shared__ int wsum[16];
    __shared__ int carrysh;
    const int tid = threadIdx.x;
    const int lane = tid & 63;
    const int wv = tid >> 6;
    if (tid == 0) carrysh = 0;
    __syncthreads();
    for (int base = 0; base < N_NODES; base += 1024) {
        int i = base + tid;
        int v = (i < N_NODES) ? deg[i] : 0;
        int s = v;
        #pragma unroll
        for (int off = 1; off < 64; off <<= 1) {
            int t = __shfl_up(s, off);
            if (lane >= off) s += t;
        }
        if (lane == 63) wsum[wv] = s;
        int carry = carrysh;
        __syncthreads();
        if (wv == 0) {
            int w = (lane < 16) ? wsum[lane] : 0;
            #pragma unroll
            for (int off = 1; off < 16; off <<= 1) {
                int t = __shfl_up(w, off);
                if (lane >= off) w += t;
            }
            if (lane < 16) wsum[lane] = w;
        }
        __syncthreads();
        int wbase = (wv > 0) ? wsum[wv - 1] : 0;
        int excl = carry + wbase + s - v;
        if (i < N_NODES) { offs[i] = excl; cursor[i] = excl; }
        int total = wsum[15];
        __syncthreads();
        if (tid == 0) carrysh = carry + total;
        __syncthreads();
    }
    if (tid == 0) offs[N_NODES] = carrysh;
}

__global__ void fill_kernel(const int* __restrict__ src, const int* __restrict__ dst,
                            int* __restrict__ cursor, int* __restrict__ csr) {
    int i = blockIdx.x * blockDim.x + threadIdx.x;
    if (i < N_EDGES) {
        int d = dst[i];
        int p = atomicAdd(&cursor[d], 1);
        csr[p] = src[i];
    }
}

// ---------------- weight convert+transpose ----------------
__global__ void wtrans_kernel(const float* __restrict__ w_neigh,
                              const float* __restrict__ w_self,
                              bf16_t* __restrict__ Bt) {
    __shared__ float tile[32][33];
    const int m = blockIdx.z;
    const bool isSelf = m >= 8;
    const int el = m & 7;
    const float* W = (isSelf ? w_self : w_neigh) + (size_t)el * DIM * DIM;
    const int k0 = blockIdx.x * 32;
    const int n0 = blockIdx.y * 32;
    const int tx = threadIdx.x, ty = threadIdx.y;
    for (int r = ty; r < 32; r += 8)
        tile[r][tx] = W[(size_t)(k0 + r) * DIM + n0 + tx];
    __syncthreads();
    for (int r = ty; r < 32; r += 8) {
        int n = n0 + r;
        int k = k0 + tx;
        Bt[((size_t)el * DIM + n) * K1 + (isSelf ? DIM : 0) + k] = (bf16_t)tile[tx][r];
    }
}

// ---------------- agg1: mean of x rows into acat cols 0..511, unroll 8 ----------------
__global__ void agg1_kernel(const int* __restrict__ offs, const int* __restrict__ csr,
                            bf16_t* __restrict__ acat) {
    const int wave = threadIdx.x >> 6;
    const int lane = threadIdx.x & 63;
    const int node = blockIdx.x * 4 + wave;
    if (node >= N_NODES) return;
    const int c0 = lane * 8;
    float s[8] = {0,0,0,0,0,0,0,0};
    int beg = offs[node];
    int end = offs[node + 1];
    int d = end - beg;
    int p = beg;
    for (; p + 8 <= end; p += 8) {
        bf16x8 v[8];
        #pragma unroll
        for (int q = 0; q < 8; q++) {
            int idx = csr[p + q];
            v[q] = *(const bf16x8*)(acat + (size_t)idx * K1 + DIM + c0);
        }
        #pragma unroll
        for (int q = 0; q < 8; q++)
            #pragma unroll
            for (int k = 0; k < 8; k++) s[k] += (float)v[q][k];
    }
    for (; p + 4 <= end; p += 4) {
        bf16x8 v[4];
        #pragma unroll
        for (int q = 0; q < 4; q++) {
            int idx = csr[p + q];
            v[q] = *(const bf16x8*)(acat + (size_t)idx * K1 + DIM + c0);
        }
        #pragma unroll
        for (int q = 0; q < 4; q++)
            #pragma unroll
            for (int k = 0; k < 8; k++) s[k] += (float)v[q][k];
    }
    for (; p < end; p++) {
        int idx = csr[p];
        bf16x8 v0 = *(const bf16x8*)(acat + (size_t)idx * K1 + DIM + c0);
        #pragma unroll
        for (int k = 0; k < 8; k++) s[k] += (float)v0[k];
    }
    float w = d > 0 ? 1.0f / (float)d : 0.0f;
    bf16x8 o;
    #pragma unroll
    for (int k = 0; k < 8; k++) o[k] = (bf16_t)(s[k] * w);
    *(bf16x8*)(acat + (size_t)node * K1 + c0) = o;
}

// ---------------- agg2: selected-expert mean of h1 rows + self copy, unroll 8 ----------------
__global__ void agg2_kernel(const int* __restrict__ offs, const int* __restrict__ csr,
                            const int* __restrict__ top_idx,
                            const bf16_t* __restrict__ h1, bf16_t* __restrict__ acat) {
    const int wave = threadIdx.x >> 6;
    const int lane = threadIdx.x & 63;
    const int node = blockIdx.x * 4 + wave;
    if (node >= N_NODES) return;
    const int c0 = lane * 8;
    const bf16_t* hb = h1 + (size_t)top_idx[node] * N_NODES * DIM;
    float s[8] = {0,0,0,0,0,0,0,0};
    int beg = offs[node];
    int end = offs[node + 1];
    int d = end - beg;
    int p = beg;
    for (; p + 8 <= end; p += 8) {
        bf16x8 v[8];
        #pragma unroll
        for (int q = 0; q < 8; q++) {
            int idx = csr[p + q];
            v[q] = *(const bf16x8*)(hb + (size_t)idx * DIM + c0);
        }
        #pragma unroll
        for (int q = 0; q < 8; q++)
            #pragma unroll
            for (int k = 0; k < 8; k++) s[k] += (float)v[q][k];
    }
    for (; p + 4 <= end; p += 4) {
        bf16x8 v[4];
        #pragma unroll
        for (int q = 0; q < 4; q++) {
            int idx = csr[p + q];
            v[q] = *(const bf16x8*)(hb + (size_t)idx * DIM + c0);
        }
        #pragma unroll
        for (int q = 0; q < 4; q++)
            #pragma unroll
            for (int k = 0; k < 8; k++) s[k] += (float)v[q][k];
    }
    for (; p < end; p++) {
        int idx = csr[p];
        bf16x8 v0 = *(const bf16x8*)(hb + (size_t)idx * DIM + c0);
        #pragma unroll
        for (int k = 0; k < 8; k++) s[k] += (float)v0[k];
    }
    float w = d > 0 ? 1.0f / (float)d : 0.0f;
    bf16x8 o;
    #pragma unroll
    for (int k = 0; k < 8; k++) o[k] = (bf16_t)(s[k] * w);
    *(bf16x8*)(acat + (size_t)node * K1 + c0) = o;
    *(bf16x8*)(acat + (size_t)node * K1 + DIM + c0) = *(const bf16x8*)(hb + (size_t)node * DIM + c0);
}

// ---------------- GEMM: 128x128 tile, BK=32, rotation-swizzled row-major LDS ----------------
// LDS: row-major, row r (0..127) = 64 B at byte r*64, holding the row's 4 k-chunks (16 B each)
// ROTATED: chunk c sits at position p = (c + (r>>1)) & 3. Staging thread t loads row t>>2 (+64),
// global chunk ((t&3) - ((t>>3)&3)) & 3 -> lands at position t&3. Consecutive 4 lanes stay inside
// one 64 B window => full coalescing. Fragment read lane L: row r, chunk c'=L>>4 at position
// (c'+(r>>1))&3 => bank-groups 4(r&1)+((c'+(r>>1))&3) cover all 8 twice => 2-way (free).
// MODE 0: 1D grid 1280 blocks, XCD-clustered decode (xcd = b&7 -> y-quarter, expert-pair)
// MODE 1: grid (4, 79, 4), row gather via lists
template <int MODE>
__global__ __launch_bounds__(256)
void gemm_kernel(const bf16_t* __restrict__ A,
                 const bf16_t* __restrict__ Bt,
                 const int layer,
                 const float* __restrict__ bias_all,
                 bf16_t* __restrict__ h1,
                 float* __restrict__ out,
                 const int* __restrict__ lists,
                 const int* __restrict__ ecnt,
                 const float* __restrict__ top_val) {
    int bx, by, e;
    if (MODE == 0) {
        const int b = blockIdx.x;
        const int kq = b & 7;
        const int ke = kq >> 2;
        const int ky = kq & 3;
        const int r = b >> 3;
        const int yloc = r >> 3;
        const int xz = r & 7;
        bx = xz & 3;
        e = ke * 2 + (xz >> 2);
        by = ky * 20 + yloc;
        if (by >= 79) return;
    } else {
        bx = blockIdx.x; by = blockIdx.y; e = blockIdx.z;
    }
    int cnt = N_NODES;
    if (MODE == 1) {
        cnt = ecnt[e];
        if (by * 128 >= cnt) return;
    }
    __shared__ __align__(16) bf16_t As[128 * 32];
    __shared__ __align__(16) bf16_t Bs[128 * 32];

    const int t = threadIdx.x;
    const int lane = t & 63;
    const int wave = t >> 6;
    const int wm = wave >> 1;
    const int wn = wave & 1;

    // staging: thread t -> LDS row r0=t>>2 (and r0+64), position p=t&3, global chunk c=(p-rot)&3
    const int r0 = t >> 2;
    const int rot = (t >> 3) & 3;                  // (r0>>1)&3
    const int cgl = ((t & 3) - rot) & 3;           // global k-chunk for this lane

    int i0 = by * 128 + r0;
    int i1 = i0 + 64;
    int arow0, arow1;
    if (MODE == 0) {
        arow0 = min(i0, N_NODES - 1);
        arow1 = min(i1, N_NODES - 1);
    } else {
        arow0 = lists[e * N_NODES + min(i0, cnt - 1)];
        arow1 = lists[e * N_NODES + min(i1, cnt - 1)];
    }
    const bf16_t* Bte = Bt + (size_t)(e * 2 + layer) * DIM * K1;
    const bf16_t* aptr0 = A + (size_t)arow0 * K1 + cgl * 8;
    const bf16_t* aptr1 = A + (size_t)arow1 * K1 + cgl * 8;
    const bf16_t* bptr0 = Bte + (size_t)(bx * 128 + r0) * K1 + cgl * 8;
    const bf16_t* bptr1 = bptr0 + (size_t)64 * K1;

    f32x4 acc[4][4] = {};
    char* asb = (char*)&As[0];
    char* bsb = (char*)&Bs[0];
    const int wb = wave * 1024;   // wave-uniform LDS base within each 4 KB half

    // fragment addresses (elements): row r_full -> r_full*32 + ((c' + (r_full>>1))&3)*8
    const int cpr = lane >> 4;       // c'
    const int rfr = lane & 15;       // row within 16-row sub-tile

    for (int k0 = 0; k0 < K1; k0 += 32) {
        __syncthreads();
        __builtin_amdgcn_global_load_lds(AS1(aptr0), AS3(asb + wb),        16, 0, 0);
        __builtin_amdgcn_global_load_lds(AS1(aptr1), AS3(asb + 4096 + wb), 16, 0, 0);
        __builtin_amdgcn_global_load_lds(AS1(bptr0), AS3(bsb + wb),        16, 0, 0);
        __builtin_amdgcn_global_load_lds(AS1(bptr1), AS3(bsb + 4096 + wb), 16, 0, 0);
        __syncthreads();
        bf16x8 af[4], bfr[4];
        #pragma unroll
        for (int i = 0; i < 4; i++) {
            int r_full = wm * 64 + i * 16 + rfr;
            int p = (cpr + (r_full >> 1)) & 3;
            af[i] = *(const bf16x8*)(As + r_full * 32 + p * 8);
        }
        #pragma unroll
        for (int j = 0; j < 4; j++) {
            int r_full = wn * 64 + j * 16 + rfr;
            int p = (cpr + (r_full >> 1)) & 3;
            bfr[j] = *(const bf16x8*)(Bs + r_full * 32 + p * 8);
        }
        #pragma unroll
        for (int i = 0; i < 4; i++)
            #pragma unroll
            for (int j = 0; j < 4; j++)
                acc[i][j] = __builtin_amdgcn_mfma_f32_16x16x32_bf16(af[i], bfr[j], acc[i][j], 0, 0, 0);
        aptr0 += 32; aptr1 += 32; bptr0 += 32; bptr1 += 32;
    }

    // epilogue; C/D layout: col=lane&15, row=(lane>>4)*4+r
    const float* bias = bias_all + e * 1024 + layer * DIM;
    const int cbase = bx * 128 + wn * 64 + (lane & 15);
    float bv[4];
    #pragma unroll
    for (int j = 0; j < 4; j++) bv[j] = bias[cbase + j * 16];
    #pragma unroll
    for (int i = 0; i < 4; i++) {
        #pragma unroll
        for (int r = 0; r < 4; r++) {
            int row = by * 128 + wm * 64 + i * 16 + (lane >> 4) * 4 + r;
            if (MODE == 0) {
                if (row < N_NODES) {
                    bf16_t* cp = h1 + ((size_t)e * N_NODES + row) * DIM + cbase;
                    #pragma unroll
                    for (int j = 0; j < 4; j++) {
                        float v = fmaxf(acc[i][j][r] + bv[j], 0.f);
                        cp[j * 16] = (bf16_t)v;
                    }
                }
            } else {
                if (row < cnt) {
                    int node = lists[e * N_NODES + row];
                    float tv = top_val[node];
                    float* cp = out + (size_t)node * DIM + cbase;
                    #pragma unroll
                    for (int j = 0; j < 4; j++) {
                        float v = fmaxf(acc[i][j][r] + bv[j], 0.f);
                        cp[j * 16] = v * tv;
                    }
                }
            }
        }
    }
}

extern "C" void kernel_launch(void* const* d_in, const int* in_sizes, int n_in,
                              void* d_out, int out_size, void* d_ws, size_t ws_size,
                              hipStream_t stream) {
    const float* x       = (const float*)d_in[0];
    const int*   edge    = (const int*)d_in[1];
    const float* gw      = (const float*)d_in[2];
    const float* gb      = (const float*)d_in[3];
    const float* w_self  = (const float*)d_in[4];
    const float* w_neigh = (const float*)d_in[5];
    const float* b_exp   = (const float*)d_in[6];
    float* out = (float*)d_out;

    char* p = (char*)d_ws;
    auto alloc = [&](size_t bytes) {
        char* r = p;
        p += (bytes + 255) & ~(size_t)255;
        return r;
    };
    bf16_t* Bt      = (bf16_t*)alloc((size_t)8 * DIM * K1 * 2);
    bf16_t* acat    = (bf16_t*)alloc((size_t)N_NODES * K1 * 2);
    bf16_t* h1      = (bf16_t*)alloc((size_t)NEXP * N_NODES * DIM * 2);
    int*    deg     = (int*)alloc((size_t)N_NODES * 4);
    int*    offs    = (int*)alloc((size_t)(N_NODES + 1) * 4);
    int*    cursor  = (int*)alloc((size_t)N_NODES * 4);
    int*    csr     = (int*)alloc((size_t)N_EDGES * 4);
    int*    top_idx = (int*)alloc((size_t)N_NODES * 4);
    float*  top_val = (float*)alloc((size_t)N_NODES * 4);
    int*    ecnt    = (int*)alloc(256);
    int*    lists   = (int*)alloc((size_t)NEXP * N_NODES * 4);

    const int* srcE = edge;
    const int* dstE = edge + N_EDGES;

    zero_kernel<<<40, 256, 0, stream>>>(deg, ecnt);
    gate_kernel<<<N_NODES / 4, 256, 0, stream>>>(x, gw, gb, top_idx, top_val, acat);
    bucket_kernel<<<40, 256, 0, stream>>>(top_idx, ecnt, lists);
    deg_kernel<<<N_EDGES / 256, 256, 0, stream>>>(dstE, deg);
    scan_kernel<<<1, 1024, 0, stream>>>(deg, offs, cursor);
    fill_kernel<<<N_EDGES / 256, 256, 0, stream>>>(srcE, dstE, cursor, csr);
    wtrans_kernel<<<dim3(16, 16, 16), dim3(32, 8), 0, stream>>>(w_neigh, w_self, Bt);
    agg1_kernel<<<N_NODES / 4, 256, 0, stream>>>(offs, csr, acat);
    gemm_kernel<0><<<1280, 256, 0, stream>>>(acat, Bt, 0, b_exp, h1, nullptr, nullptr, nullptr, nullptr);
    agg2_kernel<<<N_NODES / 4, 256, 0, stream>>>(offs, csr, top_idx, h1, acat);
    gemm_kernel<1><<<dim3(4, 79, 4), 256, 0, stream>>>(acat, Bt, 1, b_exp, nullptr, out, lists, ecnt, top_val);
}